// Round 6
// baseline (182.490 us; speedup 1.0000x reference)
//
#include <hip/hip_runtime.h>

#define NTG 128
#define NSTEPS 8191          // SEQ_LEN-1
#define GCH 512              // chunks
#define LCH 16               // steps per chunk
#define MATF16 (NTG*NTG)

typedef _Float16 half8v  __attribute__((ext_vector_type(8)));
typedef _Float16 half4v  __attribute__((ext_vector_type(4)));
typedef float    float4v __attribute__((ext_vector_type(4)));

// swizzled index into a [128][128] f16 LDS tile (element units).
// XOR bits 3..6 with row bits 0..3; preserves 8-elem (b128) alignment.
__device__ __forceinline__ int su(int row, int col){
  return (row*NTG + col) ^ ((row & 15) << 3);
}

__device__ __forceinline__ float wave_max(float v){
#pragma unroll
  for (int m = 32; m >= 1; m >>= 1) v = fmaxf(v, __shfl_xor(v, m));
  return v;
}
__device__ __forceinline__ float wave_sum(float v){
#pragma unroll
  for (int m = 32; m >= 1; m >>= 1) v += __shfl_xor(v, m);
  return v;
}

// ---------------- kernel 0: En = exp(T) f16, Et = exp(T)^T f16 ----------------
__global__ void k_prep(const float* __restrict__ T, _Float16* __restrict__ En,
                       _Float16* __restrict__ Et){
  const int idx = blockIdx.x*256 + threadIdx.x;   // 16384 total
  const int i = idx >> 7, j = idx & 127;
  const float v = __expf(T[idx]);
  En[idx] = (_Float16)v;
  Et[j*NTG + i] = (_Float16)v;
}

// ---------------- kernel 1: per-chunk transfer matrices (512 thr, 8 waves) ----------------
// Wave wv owns output rows j = wv*16 + l15. eh*pscale folded into the f16
// A-operand (one row per lane -> 1 exp/lane/step). X stored raw; Pt = (M^T)*inv.
__global__ __launch_bounds__(512, 4)
void k_chunks(const int* __restrict__ x, const float* __restrict__ emit,
              const _Float16* __restrict__ Et, const _Float16* __restrict__ En,
              _Float16* __restrict__ Pt, double* __restrict__ scale)
{
  __shared__ _Float16 X[MATF16];    // 32 KB
  __shared__ float red_g[2][8];

  const int t = threadIdx.x;
  const int lane = t & 63, wv = t >> 6;       // wv 0..7
  const int l15 = lane & 15, g4 = lane >> 4;  // g4 0..3
  const int g = blockIdx.x;
  const int s0 = g*LCH;
  const int nst = min(LCH, NSTEPS - s0);
  const int jA = wv*16 + l15;                 // this lane's A row

  // A = E^T fragments (row jA), k-slots ks*32 + g4*8 + [0..7]
  half8v aE[4];
#pragma unroll
  for (int ks=0; ks<4; ++ks)
    aE[ks] = *(const half8v*)(Et + jA*NTG + ks*32 + g4*8);

  // leaf: X = En .* exp(emit0 - m0) / 128
  double cacc;
  {
    const int tok = x[1+s0];
    const float* er = emit + (size_t)tok*NTG;
    const float2 me2 = *(const float2*)(er + (t&63)*2);
    const float m0 = wave_max(fmaxf(me2.x, me2.y));
    const float sa = __expf(me2.x - m0) * 0.0078125f;
    const float sb = __expf(me2.y - m0) * 0.0078125f;
    const int j0 = (t&63)*2;
    const unsigned int* ens = (const unsigned int*)En;
#pragma unroll
    for (int it=0; it<16; ++it){
      const int idx = it*512 + t;             // uint index; i = idx>>6, cols j0,j0+1
      union { unsigned int u; _Float16 h[2]; } pk;
      pk.u = ens[idx];
      pk.h[0] = (_Float16)((float)pk.h[0]*sa);
      pk.h[1] = (_Float16)((float)pk.h[1]*sb);
      *(unsigned int*)&X[su(idx>>6, j0)] = pk.u;
    }
    cacc = (double)m0 + 4.852030263919617;    // + log(128)
  }
  __syncthreads();

  float pscale = 1.0f;
  float4v accv[8];
  for (int s=1; s<nst; ++s){
    const int tok = x[1+s0+s];
    const float* er = emit + (size_t)tok*NTG;
    const float2 me2 = *(const float2*)(er + (t&63)*2);
    const float m = wave_max(fmaxf(me2.x, me2.y));
    const _Float16 hA = (_Float16)(__expf(er[jA] - m) * pscale);
    half8v ap[4];
#pragma unroll
    for (int ks=0; ks<4; ++ks) ap[ks] = aE[ks] * hA;

#pragma unroll
    for (int it=0; it<8; ++it) accv[it] = (float4v){0.f,0.f,0.f,0.f};

#pragma unroll
    for (int it=0; it<8; ++it){
      const int c = it*16 + l15;
      half8v bf[4];
#pragma unroll
      for (int ks=0; ks<4; ++ks)
        bf[ks] = *(const half8v*)&X[su(c, ks*32 + g4*8)];
#pragma unroll
      for (int ks=0; ks<4; ++ks)
        accv[it] = __builtin_amdgcn_mfma_f32_16x16x32_f16(ap[ks], bf[ks], accv[it], 0,0,0);
    }

    float gm = 0.f;
#pragma unroll
    for (int it=0; it<8; ++it)
#pragma unroll
      for (int r=0;r<4;r++) gm = fmaxf(gm, accv[it][r]);
    __syncthreads();                          // bar1: all X reads done
#pragma unroll
    for (int it=0; it<8; ++it){
      half4v h;
#pragma unroll
      for (int r=0;r<4;r++) h[r] = (_Float16)accv[it][r];
      *(half4v*)&X[su(it*16 + l15, wv*16 + g4*4)] = h;    // raw (unnormalized)
    }
    gm = wave_max(gm);
    if (lane==0) red_g[s&1][wv] = gm;
    __syncthreads();                          // bar2: X writes + red_g visible
    float gmax = red_g[s&1][0];
#pragma unroll
    for (int q=1;q<8;q++) gmax = fmaxf(gmax, red_g[s&1][q]);
    pscale = 1.0f/gmax;
    cacc += (double)m + (double)__logf(gmax);
  }

  // store Pt[g] = (M^T) * inv  (max-1 normalized)
  const float inv = pscale;
  unsigned int* pt = (unsigned int*)(Pt + (size_t)g*MATF16);
  const int ii = (t&63)*2;
#pragma unroll
  for (int it=0; it<16; ++it){
    const int uidx = it*512 + t;
    const int jj = uidx >> 6;
    union { unsigned int u; _Float16 h[2]; } pk;
    pk.h[0] = (_Float16)((float)X[su(ii,   jj)]*inv);
    pk.h[1] = (_Float16)((float)X[su(ii+1, jj)]*inv);
    pt[uidx] = pk.u;
  }
  if (t==0) scale[g] = cacc;
}

// ---------------- kernel 2: fan-in-8 combine (512 thr): R_k = Yt_k * R_{k-1} ----------------
__global__ __launch_bounds__(512, 2)
void k_comb8(const _Float16* __restrict__ Pt_in, const double* __restrict__ Sin,
             _Float16* __restrict__ Pt_out, double* __restrict__ Sout)
{
  __shared__ _Float16 X[MATF16];
  __shared__ float red_g[2][8];
  const int t = threadIdx.x;
  const int lane = t & 63, wv = t >> 6;
  const int l15 = lane & 15, g4 = lane >> 4;
  const int p = blockIdx.x;
  const int jA = wv*16 + l15;

  // stage X = M_{8p} from its transposed image (one-time scatter)
  {
    const unsigned int* src = (const unsigned int*)(Pt_in + (size_t)p*8*MATF16);
    const int i0 = (t&63)*2;
#pragma unroll
    for (int it=0; it<16; ++it){
      const int pos = it*512 + t;             // pair (M[i0][j], M[i0+1][j]), j = pos>>6
      union { unsigned int u; _Float16 h[2]; } pk;
      pk.u = src[pos];
      const int j = pos >> 6;
      X[su(i0,   j)] = pk.h[0];
      X[su(i0+1, j)] = pk.h[1];
    }
  }
  __syncthreads();

  float pscale = 1.0f;
  double slog = 0.0;
  float4v accv[8];
  for (int mi=1; mi<8; ++mi){
    const _Float16* Yt = Pt_in + (size_t)(p*8+mi)*MATF16;
    half8v aB[4];
#pragma unroll
    for (int ks=0; ks<4; ++ks)
      aB[ks] = *(const half8v*)(Yt + jA*NTG + ks*32 + g4*8);

#pragma unroll
    for (int it=0; it<8; ++it) accv[it] = (float4v){0.f,0.f,0.f,0.f};

#pragma unroll
    for (int it=0; it<8; ++it){
      const int c = it*16 + l15;
      half8v bf[4];
#pragma unroll
      for (int ks=0; ks<4; ++ks)
        bf[ks] = *(const half8v*)&X[su(c, ks*32 + g4*8)];
#pragma unroll
      for (int ks=0; ks<4; ++ks)
        accv[it] = __builtin_amdgcn_mfma_f32_16x16x32_f16(aB[ks], bf[ks], accv[it], 0,0,0);
    }

    float gm = 0.f;
#pragma unroll
    for (int it=0; it<8; ++it)
#pragma unroll
      for (int r=0;r<4;r++){
        const float v = accv[it][r]*pscale;   // f32 renorm (pscale may exceed f16 range)
        accv[it][r] = v;
        gm = fmaxf(gm, v);
      }
    __syncthreads();                          // bar1
#pragma unroll
    for (int it=0; it<8; ++it){
      half4v h;
#pragma unroll
      for (int r=0;r<4;r++) h[r] = (_Float16)accv[it][r];
      *(half4v*)&X[su(it*16 + l15, wv*16 + g4*4)] = h;
    }
    gm = wave_max(gm);
    if (lane==0) red_g[mi&1][wv] = gm;
    __syncthreads();                          // bar2
    float gmax = red_g[mi&1][0];
#pragma unroll
    for (int q=1;q<8;q++) gmax = fmaxf(gmax, red_g[mi&1][q]);
    pscale = 1.0f/gmax;
    slog += (double)__logf(gmax);
  }

  const float inv = pscale;
  unsigned int* pt = (unsigned int*)(Pt_out + (size_t)p*MATF16);
  const int ii = (t&63)*2;
#pragma unroll
  for (int it=0; it<16; ++it){
    const int uidx = it*512 + t;
    const int jj = uidx >> 6;
    union { unsigned int u; _Float16 h[2]; } pk;
    pk.h[0] = (_Float16)((float)X[su(ii,   jj)]*inv);
    pk.h[1] = (_Float16)((float)X[su(ii+1, jj)]*inv);
    pt[uidx] = pk.u;
  }
  if (t==0){
    double ssum = slog;
#pragma unroll
    for (int q=0;q<8;q++) ssum += Sin[p*8+q];
    Sout[p] = ssum;
  }
}

// ---------------- kernel 3: matvec chain over 8 transposed mats + final lse ----------------
__global__ void k_final(const _Float16* __restrict__ PtC, const double* __restrict__ scC,
                        const float* __restrict__ T, float* __restrict__ out)
{
  __shared__ float u[2][NTG];
  __shared__ float red[4], red2[4];
  const int t = threadIdx.x;            // 256 threads
  const int lane = t & 63, wv = t >> 6;

  double acc = 0.0;
#pragma unroll
  for (int q=0;q<8;q++) acc += scC[q];

  if (t < NTG) u[0][t] = (t==0) ? 1.f : 0.f;    // e_START
  __syncthreads();

  int cur = 0;
  const int r = t >> 1, off = (t&1)*64;
  for (int k=0;k<8;k++){
    const _Float16* Y = PtC + (size_t)k*MATF16 + (size_t)r*NTG + off;
    float dot = 0.f;
#pragma unroll
    for (int q=0;q<8;q++){
      const half8v h = *(const half8v*)(Y + q*8);
#pragma unroll
      for (int e=0;e<8;e++) dot += (float)h[e]*u[cur][off + q*8 + e];
    }
    dot += __shfl_xor(dot, 1);
    if ((t&1)==0) u[cur^1][r] = dot;    // growth <= 128^8 < f32 max: no renorm
    __syncthreads();
    cur ^= 1;
  }

  const float val = (t < NTG) ? (__logf(u[cur][t]) + T[t*NTG + 1]) : -3.0e38f;
  float mx = wave_max(val);
  if (lane==0) red[wv] = mx;
  __syncthreads();
  mx = fmaxf(fmaxf(red[0],red[1]), fmaxf(red[2],red[3]));
  const float e = (t < NTG) ? __expf(val - mx) : 0.f;
  const float s = wave_sum(e);
  if (lane==0) red2[wv] = s;
  __syncthreads();
  if (t==0){
    const double z = (double)mx + log((double)(red2[0]+red2[1]+red2[2]+red2[3])) + acc;
    out[0] = (float)z;
  }
}

extern "C" void kernel_launch(void* const* d_in, const int* in_sizes, int n_in,
                              void* d_out, int out_size, void* d_ws, size_t ws_size,
                              hipStream_t stream)
{
  const int*   x    = (const int*)d_in[0];
  const float* emit = (const float*)d_in[1];
  const float* T    = (const float*)d_in[2];
  float* out = (float*)d_out;

  // ws (f16): En[1] Et[1] PtA[512] PtB[64] PtC[8] | dbl scA[512] scB[64] scC[8]  (~19.3 MB)
  _Float16* En  = (_Float16*)d_ws;
  _Float16* Et  = En  + MATF16;
  _Float16* PtA = Et  + MATF16;
  _Float16* PtB = PtA + (size_t)512*MATF16;
  _Float16* PtC = PtB + (size_t)64*MATF16;
  double* scA = (double*)(PtC + (size_t)8*MATF16);
  double* scB = scA + 512;
  double* scC = scB + 64;

  k_prep<<<64, 256, 0, stream>>>(T, En, Et);
  k_chunks<<<GCH, 512, 0, stream>>>(x, emit, Et, En, PtA, scA);
  k_comb8<<<64, 512, 0, stream>>>(PtA, scA, PtB, scB);
  k_comb8<<< 8, 512, 0, stream>>>(PtB, scB, PtC, scC);
  k_final<<<1, 256, 0, stream>>>(PtC, scC, T, out);
}

// Round 7
// 171.859 us; speedup vs baseline: 1.0619x; 1.0619x over previous
//
#include <hip/hip_runtime.h>

#define NTG 128
#define NSTEPS 8191          // SEQ_LEN-1
#define GCH 512              // chunks
#define LCH 16               // steps per chunk
#define MATF16 (NTG*NTG)

typedef _Float16 half8v  __attribute__((ext_vector_type(8)));
typedef _Float16 half4v  __attribute__((ext_vector_type(4)));
typedef float    float4v __attribute__((ext_vector_type(4)));

// swizzled index into a [128][128] f16 LDS tile (element units).
// XOR bits 3..6 with row bits 0..3; preserves 8-elem (b128) alignment.
__device__ __forceinline__ int su(int row, int col){
  return (row*NTG + col) ^ ((row & 15) << 3);
}

__device__ __forceinline__ float wave_max(float v){
#pragma unroll
  for (int m = 32; m >= 1; m >>= 1) v = fmaxf(v, __shfl_xor(v, m));
  return v;
}
__device__ __forceinline__ float wave_sum(float v){
#pragma unroll
  for (int m = 32; m >= 1; m >>= 1) v += __shfl_xor(v, m);
  return v;
}

__device__ __forceinline__ float red8(const float* rg){
  const float4v r0 = *(const float4v*)rg;
  const float4v r1 = *(const float4v*)(rg+4);
  return fmaxf(fmaxf(fmaxf(r0[0],r0[1]),fmaxf(r0[2],r0[3])),
               fmaxf(fmaxf(r1[0],r1[1]),fmaxf(r1[2],r1[3])));
}

// ---------------- kernel 1: per-chunk transfer matrices ----------------
// Wave (wr,wc) = (wv>>1, wv&1) owns D rows j in [wr*32,+32), cols i in [wc*64,+64).
// Triple-dbuf (X/ehl/red_g) -> ONE barrier per step. Wave 0 alone builds the
// per-step emit-exp table. Row scale eh[j]*pscale applied on D (pscale scalar).
__global__ __launch_bounds__(512, 4)
void k_chunks(const int* __restrict__ x, const float* __restrict__ emit,
              const float* __restrict__ T, _Float16* __restrict__ Pt,
              double* __restrict__ scale)
{
  __shared__ _Float16 X[2][MATF16];      // 64 KB
  __shared__ float ehl[2][NTG];
  __shared__ float red_g[2][8];

  const int t = threadIdx.x, lane = t & 63, wv = t >> 6;
  const int l15 = lane & 15, g4 = lane >> 4;
  const int wr = wv >> 1, wc = wv & 1;
  const int g = blockIdx.x, s0 = g*LCH;
  const int nst = min(LCH, NSTEPS - s0);

  // static A = E^T fragments: A[j][k] = exp(T[k][j]); j = wr*32+rt*16+l15
  half8v aE[2][4];
#pragma unroll
  for (int rt=0; rt<2; ++rt){
    const int j = wr*32 + rt*16 + l15;
#pragma unroll
    for (int ks=0; ks<4; ++ks){
      half8v a;
#pragma unroll
      for (int jj=0; jj<8; ++jj)
        a[jj] = (_Float16)__expf(T[(ks*32 + g4*8 + jj)*NTG + j]);
      aE[rt][ks] = a;
    }
  }

  int tokv = 0;
  if (wv==0) tokv = x[1 + s0 + min(lane, nst-1)];   // lanes 0..15 hold the tokens

  double cacc = 0.0;
  // leaf: X[1] = exp(T) .* exp(er0 - m0)/128 ; wave0 writes ehl[1]; red_g[0]=1
  {
    const int tok0 = x[1+s0];
    const float2 e0 = *(const float2*)(emit + (size_t)tok0*NTG + lane*2);
    const float m0 = wave_max(fmaxf(e0.x, e0.y));
    const float sa = __expf(e0.x - m0)*0.0078125f;
    const float sb = __expf(e0.y - m0)*0.0078125f;
    const int j0 = lane*2;
#pragma unroll
    for (int it=0; it<16; ++it){
      const int idx = it*512 + t;              // uint idx over 8192
      const int i = idx >> 6;
      const float2 tv = *(const float2*)(T + (size_t)i*NTG + j0);
      union { unsigned u; _Float16 h[2]; } pk;
      pk.h[0] = (_Float16)(__expf(tv.x)*sa);
      pk.h[1] = (_Float16)(__expf(tv.y)*sb);
      *(unsigned*)&X[1][su(i, j0)] = pk.u;
    }
    if (t==0) cacc = (double)m0 + 4.852030263919617;   // + log 128
    if (wv==0){
      const int tok1 = __shfl(tokv, 1);
      const float2 e1 = *(const float2*)(emit + (size_t)tok1*NTG + lane*2);
      const float m1 = wave_max(fmaxf(e1.x, e1.y));
      *(float2*)&ehl[1][lane*2] = make_float2(__expf(e1.x-m1), __expf(e1.y-m1));
      if (t==0) cacc += (double)m1;
    }
    if (t<8) red_g[0][t] = 1.0f;
  }

  float4v accv[2][4];
  for (int s=1; s<nst; ++s){
    __syncthreads();                                   // the ONLY barrier/step
    const float gmax = red8(&red_g[(s-1)&1][0]);
    const float pscale = 1.0f/gmax;
    if (t==0) cacc += (double)__logf(gmax);            // log(1)=0 at s==1

#pragma unroll
    for (int rt=0;rt<2;++rt)
#pragma unroll
      for (int ct=0;ct<4;++ct) accv[rt][ct] = (float4v){0.f,0.f,0.f,0.f};

    const _Float16* __restrict__ Xs = X[s&1];
#pragma unroll
    for (int ct=0; ct<4; ++ct){
      const int c = wc*64 + ct*16 + l15;
      half8v bf[4];
#pragma unroll
      for (int ks=0;ks<4;++ks)
        bf[ks] = *(const half8v*)&Xs[su(c, ks*32 + g4*8)];
#pragma unroll
      for (int rt=0;rt<2;++rt)
#pragma unroll
        for (int ks=0;ks<4;++ks)
          accv[rt][ct] = __builtin_amdgcn_mfma_f32_16x16x32_f16(aE[rt][ks], bf[ks], accv[rt][ct], 0,0,0);
    }

    if (wv==0 && s+1<nst){                             // emit table for step s+1
      const int tokn = __shfl(tokv, s+1);
      const float2 en = *(const float2*)(emit + (size_t)tokn*NTG + lane*2);
      const float mn = wave_max(fmaxf(en.x,en.y));
      *(float2*)&ehl[(s+1)&1][lane*2] = make_float2(__expf(en.x-mn), __expf(en.y-mn));
      if (t==0) cacc += (double)mn;
    }

    float gm = 0.f;
    _Float16* __restrict__ Xd = X[(s+1)&1];
#pragma unroll
    for (int rt=0;rt<2;++rt){
      const float4v eh4 = *(const float4v*)&ehl[s&1][wr*32 + rt*16 + g4*4];
#pragma unroll
      for (int ct=0;ct<4;++ct){
        half4v h;
#pragma unroll
        for (int r=0;r<4;r++){
          const float v = accv[rt][ct][r]*eh4[r]*pscale;
          gm = fmaxf(gm, v);
          h[r] = (_Float16)v;
        }
        *(half4v*)&Xd[su(wc*64 + ct*16 + l15, wr*32 + rt*16 + g4*4)] = h;
      }
    }
    gm = wave_max(gm);
    if (lane==0) red_g[s&1][wv] = gm;
  }

  __syncthreads();
  {
    const float gmaxF = red8(&red_g[(nst-1)&1][0]);
    const float inv = 1.0f/gmaxF;
    const _Float16* __restrict__ Xf = X[nst&1];
    unsigned* pt = (unsigned*)(Pt + (size_t)g*MATF16);
#pragma unroll
    for (int it=0; it<16; ++it){
      const int uidx = it*512 + t;
      const int jj = uidx >> 6, ii = (uidx & 63)*2;
      union { unsigned u; _Float16 h[2]; } pk;
      pk.h[0] = (_Float16)((float)Xf[su(ii,   jj)]*inv);
      pk.h[1] = (_Float16)((float)Xf[su(ii+1, jj)]*inv);
      pt[uidx] = pk.u;                                 // Pt[j][i] = M[i][j]
    }
    if (t==0) scale[g] = cacc + (double)__logf(gmaxF);
  }
}

// ---------------- kernel 2: fan-in-8 combine, prefetched A, 1 bar/matmul ----------------
// X = R (normal orientation); R' = R*Y_mi computed as D[j][i] = sum_k Yt[j][k]*X[i][k].
__global__ __launch_bounds__(512, 2)
void k_comb8(const _Float16* __restrict__ Pt_in, const double* __restrict__ Sin,
             _Float16* __restrict__ Pt_out, double* __restrict__ Sout)
{
  __shared__ _Float16 X[2][MATF16];
  __shared__ float red_g[2][8];
  const int t = threadIdx.x, lane = t & 63, wv = t >> 6;
  const int l15 = lane & 15, g4 = lane >> 4;
  const int wr = wv >> 1, wc = wv & 1;
  const int p = blockIdx.x;
  const _Float16* __restrict__ base = Pt_in + (size_t)p*8*MATF16;

  // stage X[1] = M_{8p} from its transposed image
  {
    const unsigned* src = (const unsigned*)base;
#pragma unroll
    for (int it=0; it<16; ++it){
      const int pos = it*512 + t;
      union { unsigned u; _Float16 h[2]; } pk;
      pk.u = src[pos];
      const int jj = pos >> 6, ii = (pos & 63)*2;
      X[1][su(ii,   jj)] = pk.h[0];
      X[1][su(ii+1, jj)] = pk.h[1];
    }
    if (t<8) red_g[0][t] = 1.0f;
  }

  // preload A for mi=1: rows of Yt (contiguous)
  half8v aB[2][4];
#pragma unroll
  for (int rt=0;rt<2;++rt)
#pragma unroll
    for (int ks=0;ks<4;++ks)
      aB[rt][ks] = *(const half8v*)(base + MATF16 + (size_t)(wr*32+rt*16+l15)*NTG + ks*32 + g4*8);

  double slog = 0.0;
  float4v accv[2][4];
#pragma unroll
  for (int mi=1; mi<8; ++mi){
    __syncthreads();
    const float gmax = red8(&red_g[(mi-1)&1][0]);
    const float pscale = 1.0f/gmax;
    if (t==0) slog += (double)__logf(gmax);

#pragma unroll
    for (int rt=0;rt<2;++rt)
#pragma unroll
      for (int ct=0;ct<4;++ct) accv[rt][ct] = (float4v){0.f,0.f,0.f,0.f};

    const _Float16* __restrict__ Xs = X[mi&1];
#pragma unroll
    for (int ct=0; ct<4; ++ct){
      const int c = wc*64 + ct*16 + l15;
      half8v bf[4];
#pragma unroll
      for (int ks=0;ks<4;++ks)
        bf[ks] = *(const half8v*)&Xs[su(c, ks*32 + g4*8)];
#pragma unroll
      for (int rt=0;rt<2;++rt)
#pragma unroll
        for (int ks=0;ks<4;++ks)
          accv[rt][ct] = __builtin_amdgcn_mfma_f32_16x16x32_f16(aB[rt][ks], bf[ks], accv[rt][ct], 0,0,0);
    }

    half8v aBn[2][4];
    if (mi<7){                                          // prefetch next A
#pragma unroll
      for (int rt=0;rt<2;++rt)
#pragma unroll
        for (int ks=0;ks<4;++ks)
          aBn[rt][ks] = *(const half8v*)(base + (size_t)(mi+1)*MATF16 + (size_t)(wr*32+rt*16+l15)*NTG + ks*32 + g4*8);
    }

    float gm = 0.f;
    _Float16* __restrict__ Xd = X[(mi+1)&1];
#pragma unroll
    for (int rt=0;rt<2;++rt)
#pragma unroll
      for (int ct=0;ct<4;++ct){
        half4v h;
#pragma unroll
        for (int r=0;r<4;r++){
          const float v = accv[rt][ct][r]*pscale;
          gm = fmaxf(gm, v);
          h[r] = (_Float16)v;
        }
        *(half4v*)&Xd[su(wc*64 + ct*16 + l15, wr*32 + rt*16 + g4*4)] = h;
      }
    gm = wave_max(gm);
    if (lane==0) red_g[mi&1][wv] = gm;

    if (mi<7){
#pragma unroll
      for (int rt=0;rt<2;++rt)
#pragma unroll
        for (int ks=0;ks<4;++ks) aB[rt][ks] = aBn[rt][ks];
    }
  }

  __syncthreads();
  {
    const float gmaxF = red8(&red_g[1][0]);             // (7)&1 = 1
    const float inv = 1.0f/gmaxF;
    const _Float16* __restrict__ Xf = X[0];             // (7+1)&1 = 0
    unsigned* pt = (unsigned*)(Pt_out + (size_t)p*MATF16);
#pragma unroll
    for (int it=0; it<16; ++it){
      const int uidx = it*512 + t;
      const int jj = uidx >> 6, ii = (uidx & 63)*2;
      union { unsigned u; _Float16 h[2]; } pk;
      pk.h[0] = (_Float16)((float)Xf[su(ii,   jj)]*inv);
      pk.h[1] = (_Float16)((float)Xf[su(ii+1, jj)]*inv);
      pt[uidx] = pk.u;
    }
    if (t==0){
      double ssum = slog + (double)__logf(gmaxF);
#pragma unroll
      for (int q=0;q<8;q++) ssum += Sin[p*8+q];
      Sout[p] = ssum;
    }
  }
}

// ---------------- kernel 3: matvec chain over 8 transposed mats + final lse ----------------
__global__ void k_final(const _Float16* __restrict__ PtC, const double* __restrict__ scC,
                        const float* __restrict__ T, float* __restrict__ out)
{
  __shared__ float u[2][NTG];
  __shared__ float red[4], red2[4];
  const int t = threadIdx.x;            // 256 threads
  const int lane = t & 63, wv = t >> 6;

  double acc = 0.0;
#pragma unroll
  for (int q=0;q<8;q++) acc += scC[q];

  if (t < NTG) u[0][t] = (t==0) ? 1.f : 0.f;    // e_START
  __syncthreads();

  int cur = 0;
  const int r = t >> 1, off = (t&1)*64;
  for (int k=0;k<8;k++){
    const _Float16* Y = PtC + (size_t)k*MATF16 + (size_t)r*NTG + off;
    float dot = 0.f;
#pragma unroll
    for (int q=0;q<8;q++){
      const half8v h = *(const half8v*)(Y + q*8);
#pragma unroll
      for (int e=0;e<8;e++) dot += (float)h[e]*u[cur][off + q*8 + e];
    }
    dot += __shfl_xor(dot, 1);
    if ((t&1)==0) u[cur^1][r] = dot;    // growth <= 128^8 < f32 max: no renorm
    __syncthreads();
    cur ^= 1;
  }

  const float val = (t < NTG) ? (__logf(u[cur][t]) + T[t*NTG + 1]) : -3.0e38f;
  float mx = wave_max(val);
  if (lane==0) red[wv] = mx;
  __syncthreads();
  mx = fmaxf(red[0], red[1]);
  const float e = (t < NTG) ? __expf(val - mx) : 0.f;
  const float s = wave_sum(e);
  if (lane==0) red2[wv] = s;
  __syncthreads();
  if (t==0){
    const double z = (double)mx + log((double)(red2[0]+red2[1])) + acc;
    out[0] = (float)z;
  }
}

extern "C" void kernel_launch(void* const* d_in, const int* in_sizes, int n_in,
                              void* d_out, int out_size, void* d_ws, size_t ws_size,
                              hipStream_t stream)
{
  const int*   x    = (const int*)d_in[0];
  const float* emit = (const float*)d_in[1];
  const float* T    = (const float*)d_in[2];
  float* out = (float*)d_out;

  // ws (f16): PtA[512] PtB[64] PtC[8] | dbl scA[512] scB[64] scC[8]  (~18.9 MB)
  _Float16* PtA = (_Float16*)d_ws;
  _Float16* PtB = PtA + (size_t)512*MATF16;
  _Float16* PtC = PtB + (size_t)64*MATF16;
  double* scA = (double*)(PtC + (size_t)8*MATF16);
  double* scB = scA + 512;
  double* scC = scB + 64;

  k_chunks<<<GCH, 512, 0, stream>>>(x, emit, T, PtA, scA);
  k_comb8<<<64, 512, 0, stream>>>(PtA, scA, PtB, scB);
  k_comb8<<< 8, 512, 0, stream>>>(PtB, scB, PtC, scC);
  k_final<<<1, 256, 0, stream>>>(PtC, scC, T, out);
}